// Round 1
// baseline (129.725 us; speedup 1.0000x reference)
//
#include <hip/hip_runtime.h>
#include <hip/hip_bf16.h>

#define NPOS   100
#define BATCH  1024
#define DIN    384
#define DOUT   384
#define XROW   (NPOS * DIN)      // 38400 floats, stride of batch dim (x and out)
#define WSLICE (DIN * DOUT)      // 147456 floats per weight slice

#define BM 128
#define BN 128
#define BK 32
#define NK (DIN / BK)            // 12 K-steps
#define PITCH 40                 // LDS row pitch in bf16 elems (128B-friendly pad)

typedef __attribute__((ext_vector_type(8))) short bf16x8;
typedef __attribute__((ext_vector_type(4))) float f32x4;

__device__ __forceinline__ unsigned short f2bf(float f) {
  __hip_bfloat16 h = __float2bfloat16(f);
  return __builtin_bit_cast(unsigned short, h);
}

__device__ __forceinline__ uint2 pack4(float a, float b, float c, float d) {
  uint2 r;
  r.x = (unsigned)f2bf(a) | ((unsigned)f2bf(b) << 16);
  r.y = (unsigned)f2bf(c) | ((unsigned)f2bf(d) << 16);
  return r;
}

__global__ __launch_bounds__(256, 2) void nlinear_kernel(
    const float* __restrict__ x, const float* __restrict__ w,
    const float* __restrict__ bias, float* __restrict__ out)
{
  // A: x-tile rows (b) x k, row-major. B: weight stored TRANSPOSED (o rows, k cols).
  __shared__ short lA[2][BM * PITCH];
  __shared__ short lB[2][BN * PITCH];

  const int tid  = threadIdx.x;
  const int lane = tid & 63;
  const int wave = tid >> 6;
  const int wm   = wave >> 1;           // 2x2 wave grid, each wave 64x64
  const int wn   = wave & 1;
  const int lr   = lane & 15;           // frag row/col within 16x16
  const int lko  = (lane >> 4) << 3;    // k offset (8 contiguous bf16 per lane)

  // XCD-aware bijective swizzle: 2400 blocks = 8 * 300
  const int bid   = blockIdx.x;
  const int swz   = (bid & 7) * 300 + (bid >> 3);
  const int slice = swz / 24;
  const int rem   = swz - slice * 24;
  const int mt    = rem / 3;
  const int nt    = rem - mt * 3;

  const float* xbase = x    + (size_t)mt * BM * XROW + (size_t)slice * DIN;
  const float* wbase = w    + (size_t)slice * WSLICE + nt * BN;
  const float* bbase = bias + (size_t)slice * DOUT   + nt * BN;
  float*       obase = out  + (size_t)mt * BM * XROW + (size_t)slice * DOUT + nt * BN;

  // Staging decomposition (all loads 128B-coalesced per 8-lane group):
  // A: thread covers 4 float4s: row = (tid>>3) + 32*i, k-chunk = tid&7
  // B: thread covers a 4k x 4o block: kb = tid&7 (k-block), o4 = tid>>3 (o-block)
  const int a_c4   = tid & 7;
  const int a_row0 = tid >> 3;
  const int b_kb   = tid & 7;
  const int b_o4   = tid >> 3;

  float gav[4][4];
  float gbv[4][4];

  auto G2R = [&](int k0) {
#pragma unroll
    for (int i = 0; i < 4; ++i) {
      const float4 v = *reinterpret_cast<const float4*>(
          xbase + (size_t)(a_row0 + 32 * i) * XROW + k0 + a_c4 * 4);
      gav[i][0] = v.x; gav[i][1] = v.y; gav[i][2] = v.z; gav[i][3] = v.w;
    }
#pragma unroll
    for (int dk = 0; dk < 4; ++dk) {
      const float4 v = *reinterpret_cast<const float4*>(
          wbase + (size_t)(k0 + b_kb * 4 + dk) * DOUT + b_o4 * 4);
      gbv[dk][0] = v.x; gbv[dk][1] = v.y; gbv[dk][2] = v.z; gbv[dk][3] = v.w;
    }
  };

  auto R2L = [&](int buf) {
#pragma unroll
    for (int i = 0; i < 4; ++i) {
      *reinterpret_cast<uint2*>(
          &lA[buf][(a_row0 + 32 * i) * PITCH + a_c4 * 4]) =
          pack4(gav[i][0], gav[i][1], gav[i][2], gav[i][3]);
    }
    // in-register 4x4 transpose: write B^T rows (o), cols (k)
#pragma unroll
    for (int j = 0; j < 4; ++j) {
      *reinterpret_cast<uint2*>(
          &lB[buf][(b_o4 * 4 + j) * PITCH + b_kb * 4]) =
          pack4(gbv[0][j], gbv[1][j], gbv[2][j], gbv[3][j]);
    }
  };

  f32x4 acc[4][4];
#pragma unroll
  for (int m = 0; m < 4; ++m)
#pragma unroll
    for (int n = 0; n < 4; ++n)
      acc[m][n] = f32x4{0.f, 0.f, 0.f, 0.f};

  G2R(0);
  R2L(0);
  __syncthreads();
  G2R(BK);  // prefetch step 1

  auto STEP = [&](int ks, int cb) {
    if (ks + 1 < NK) R2L(cb ^ 1);     // stage next tile (uses loads from ks+1)
    bf16x8 af[4], bfv[4];
#pragma unroll
    for (int m = 0; m < 4; ++m)
      af[m] = *reinterpret_cast<const bf16x8*>(
          &lA[cb][(wm * 64 + m * 16 + lr) * PITCH + lko]);
#pragma unroll
    for (int n = 0; n < 4; ++n)
      bfv[n] = *reinterpret_cast<const bf16x8*>(
          &lB[cb][(wn * 64 + n * 16 + lr) * PITCH + lko]);
    if (ks + 2 < NK) G2R((ks + 2) * BK);  // issue loads for step ks+2 (hide HBM latency)
#pragma unroll
    for (int m = 0; m < 4; ++m)
#pragma unroll
      for (int n = 0; n < 4; ++n)
        acc[m][n] = __builtin_amdgcn_mfma_f32_16x16x32_bf16(
            af[m], bfv[n], acc[m][n], 0, 0, 0);
    __syncthreads();
  };

  for (int ks = 0; ks < NK; ks += 2) {
    STEP(ks, 0);
    STEP(ks + 1, 1);
  }

  // Epilogue: bias add + fp32 store. D frag: col = lane&15, row = (lane>>4)*4 + r
  float bv[4];
#pragma unroll
  for (int n = 0; n < 4; ++n) bv[n] = bbase[wn * 64 + n * 16 + lr];

  const int rbase = wm * 64 + ((lane >> 4) << 2);
#pragma unroll
  for (int m = 0; m < 4; ++m) {
#pragma unroll
    for (int n = 0; n < 4; ++n) {
      const int c = wn * 64 + n * 16 + lr;
#pragma unroll
      for (int r = 0; r < 4; ++r) {
        obase[(size_t)(rbase + m * 16 + r) * XROW + c] = acc[m][n][r] + bv[n];
      }
    }
  }
}

extern "C" void kernel_launch(void* const* d_in, const int* in_sizes, int n_in,
                              void* d_out, int out_size, void* d_ws, size_t ws_size,
                              hipStream_t stream) {
  const float* x  = (const float*)d_in[0];
  const float* w  = (const float*)d_in[1];
  const float* b  = (const float*)d_in[2];
  float* out      = (float*)d_out;
  const int grid  = NPOS * (BATCH / BM) * (DOUT / BN);  // 2400
  nlinear_kernel<<<grid, 256, 0, stream>>>(x, w, b, out);
}

// Round 2
// 127.552 us; speedup vs baseline: 1.0170x; 1.0170x over previous
//
#include <hip/hip_runtime.h>
#include <hip/hip_bf16.h>

#define NPOS   100
#define BATCH  1024
#define DIN    384
#define DOUT   384
#define XROW   (NPOS * DIN)      // 38400 floats, stride of batch dim (x and out)
#define WSLICE (DIN * DOUT)      // 147456 floats per weight slice

#define BM 128
#define BN 128
#define BK 32
#define NK (DIN / BK)            // 12 K-steps
#define PITCH 40                 // 80B rows: 16B-aligned for b128, 2-way banks (free)

typedef __attribute__((ext_vector_type(8))) short bf16x8;
typedef __attribute__((ext_vector_type(4))) float f32x4;

__device__ __forceinline__ unsigned short f2bf(float f) {
  __hip_bfloat16 h = __float2bfloat16(f);
  return __builtin_bit_cast(unsigned short, h);
}

__device__ __forceinline__ uint2 pack4(float a, float b, float c, float d) {
  uint2 r;
  r.x = (unsigned)f2bf(a) | ((unsigned)f2bf(b) << 16);
  r.y = (unsigned)f2bf(c) | ((unsigned)f2bf(d) << 16);
  return r;
}

// lgkmcnt(0) + raw barrier: ds ops visible, but vmcnt NOT drained -> global
// prefetch survives across the barrier (the whole point of this round).
__device__ __forceinline__ void barrier_nodrain() {
  asm volatile("s_waitcnt lgkmcnt(0)" ::: "memory");
  __builtin_amdgcn_s_barrier();
}

__global__ __launch_bounds__(256, 4) void nlinear_kernel(
    const float* __restrict__ x, const float* __restrict__ w,
    const float* __restrict__ bias, float* __restrict__ out)
{
  __shared__ short lA[2][BM * PITCH];
  __shared__ short lB[2][BN * PITCH];

  const int tid  = threadIdx.x;
  const int lane = tid & 63;
  const int wave = tid >> 6;
  const int wm   = wave >> 1;           // 2x2 wave grid, each wave 64x64
  const int wn   = wave & 1;
  const int lr   = lane & 15;
  const int lko  = (lane >> 4) << 3;

  // XCD-aware bijective swizzle: 2400 blocks = 8 * 300
  const int bid   = blockIdx.x;
  const int swz   = (bid & 7) * 300 + (bid >> 3);
  const int slice = swz / 24;
  const int rem   = swz - slice * 24;
  const int mt    = rem / 3;
  const int nt    = rem - mt * 3;

  const float* xbase = x    + (size_t)mt * BM * XROW + (size_t)slice * DIN;
  const float* wbase = w    + (size_t)slice * WSLICE + nt * BN;
  const float* bbase = bias + (size_t)slice * DOUT   + nt * BN;
  float*       obase = out  + (size_t)mt * BM * XROW + (size_t)slice * DOUT + nt * BN;

  const int a_c4   = tid & 7;
  const int a_row0 = tid >> 3;
  const int b_kb   = tid & 7;
  const int b_o4   = tid >> 3;

  float gav[4][4];
  float gbv[4][4];

  auto G2R = [&](int k0) {
#pragma unroll
    for (int i = 0; i < 4; ++i) {
      const float4 v = *reinterpret_cast<const float4*>(
          xbase + (size_t)(a_row0 + 32 * i) * XROW + k0 + a_c4 * 4);
      gav[i][0] = v.x; gav[i][1] = v.y; gav[i][2] = v.z; gav[i][3] = v.w;
    }
#pragma unroll
    for (int dk = 0; dk < 4; ++dk) {
      const float4 v = *reinterpret_cast<const float4*>(
          wbase + (size_t)(k0 + b_kb * 4 + dk) * DOUT + b_o4 * 4);
      gbv[dk][0] = v.x; gbv[dk][1] = v.y; gbv[dk][2] = v.z; gbv[dk][3] = v.w;
    }
  };

  auto R2L = [&](int buf) {
#pragma unroll
    for (int i = 0; i < 4; ++i) {
      *reinterpret_cast<uint2*>(
          &lA[buf][(a_row0 + 32 * i) * PITCH + a_c4 * 4]) =
          pack4(gav[i][0], gav[i][1], gav[i][2], gav[i][3]);
    }
#pragma unroll
    for (int j = 0; j < 4; ++j) {
      *reinterpret_cast<uint2*>(
          &lB[buf][(b_o4 * 4 + j) * PITCH + b_kb * 4]) =
          pack4(gbv[0][j], gbv[1][j], gbv[2][j], gbv[3][j]);
    }
  };

  f32x4 acc[4][4];
#pragma unroll
  for (int m = 0; m < 4; ++m)
#pragma unroll
    for (int n = 0; n < 4; ++n)
      acc[m][n] = f32x4{0.f, 0.f, 0.f, 0.f};

  G2R(0);
  R2L(0);
  barrier_nodrain();
  G2R(BK);  // prefetch step 1 — stays in flight across barriers now

  auto STEP = [&](int ks, int cb) {
    if (ks + 1 < NK) R2L(cb ^ 1);     // compiler waits vmcnt for prev G2R here
    if (ks + 2 < NK) G2R((ks + 2) * BK);  // issue next loads ASAP
    bf16x8 af[4], bfv[4];
#pragma unroll
    for (int m = 0; m < 4; ++m)
      af[m] = *reinterpret_cast<const bf16x8*>(
          &lA[cb][(wm * 64 + m * 16 + lr) * PITCH + lko]);
#pragma unroll
    for (int n = 0; n < 4; ++n)
      bfv[n] = *reinterpret_cast<const bf16x8*>(
          &lB[cb][(wn * 64 + n * 16 + lr) * PITCH + lko]);
#pragma unroll
    for (int m = 0; m < 4; ++m)
#pragma unroll
      for (int n = 0; n < 4; ++n)
        acc[m][n] = __builtin_amdgcn_mfma_f32_16x16x32_bf16(
            af[m], bfv[n], acc[m][n], 0, 0, 0);
    barrier_nodrain();   // lgkmcnt(0) only: ds_writes visible, vmcnt survives
  };

#pragma unroll
  for (int ks = 0; ks < NK; ks += 2) {
    STEP(ks, 0);
    STEP(ks + 1, 1);
  }

  // Epilogue: bias add + fp32 store. D frag: col = lane&15, row = (lane>>4)*4 + r
  float bv[4];
#pragma unroll
  for (int n = 0; n < 4; ++n) bv[n] = bbase[wn * 64 + n * 16 + lr];

  const int rbase = wm * 64 + ((lane >> 4) << 2);
#pragma unroll
  for (int m = 0; m < 4; ++m) {
#pragma unroll
    for (int n = 0; n < 4; ++n) {
      const int c = wn * 64 + n * 16 + lr;
#pragma unroll
      for (int r = 0; r < 4; ++r) {
        obase[(size_t)(rbase + m * 16 + r) * XROW + c] = acc[m][n][r] + bv[n];
      }
    }
  }
}

extern "C" void kernel_launch(void* const* d_in, const int* in_sizes, int n_in,
                              void* d_out, int out_size, void* d_ws, size_t ws_size,
                              hipStream_t stream) {
  const float* x  = (const float*)d_in[0];
  const float* w  = (const float*)d_in[1];
  const float* b  = (const float*)d_in[2];
  float* out      = (float*)d_out;
  const int grid  = NPOS * (BATCH / BM) * (DOUT / BN);  // 2400
  nlinear_kernel<<<grid, 256, 0, stream>>>(x, w, b, out);
}

// Round 3
// 117.093 us; speedup vs baseline: 1.1079x; 1.0893x over previous
//
#include <hip/hip_runtime.h>
#include <hip/hip_bf16.h>

#define NPOS   100
#define BATCH  1024
#define DIN    384
#define DOUT   384
#define XROW   (NPOS * DIN)      // 38400 floats, batch-dim stride of x and out
#define WSLICE (DIN * DOUT)

#define BM 128
#define BN 128
#define BK 32
#define NK (DIN / BK)            // 12 K-steps
#define PITCH 40                 // A rows: 80B (16B-aligned for b128, 2-way banks)
#define BPITCH 132               // B rows: 264B (8B-aligned; 4 lane-groups -> disjoint banks)

typedef __attribute__((ext_vector_type(8))) short bf16x8;
typedef __attribute__((ext_vector_type(16))) float f32x16;

__device__ __forceinline__ unsigned short f2bf(float f) {
  __hip_bfloat16 h = __float2bfloat16(f);
  return __builtin_bit_cast(unsigned short, h);
}

__device__ __forceinline__ uint2 pack4(float a, float b, float c, float d) {
  uint2 r;
  r.x = (unsigned)f2bf(a) | ((unsigned)f2bf(b) << 16);
  r.y = (unsigned)f2bf(c) | ((unsigned)f2bf(d) << 16);
  return r;
}

// ds ops visible, vmcnt NOT drained (prefetch survives the barrier)
__device__ __forceinline__ void barrier_nodrain() {
  asm volatile("s_waitcnt lgkmcnt(0)" ::: "memory");
  __builtin_amdgcn_s_barrier();
}

__global__ __launch_bounds__(256, 3) void nlinear_kernel(
    const float* __restrict__ x, const float* __restrict__ w,
    const float* __restrict__ bias, float* __restrict__ out)
{
  __shared__ short lA[2][BM * PITCH];    // [row][k] bf16
  __shared__ short lB[2][BK * BPITCH];   // [k][o]  bf16 (natural layout, no transpose)

  const int tid  = threadIdx.x;
  const int lane = tid & 63;
  const int wave = tid >> 6;
  const int wm   = wave >> 1;            // 2x2 wave grid, each wave 64x64
  const int wn   = wave & 1;
  const int l31  = lane & 31;
  const int kHi  = (lane >> 5) * 8;      // k sub-offset within mfma fragment

  // XCD-aware bijective swizzle: 2400 blocks = 8 * 300
  const int bid   = blockIdx.x;
  const int swz   = (bid & 7) * 300 + (bid >> 3);
  const int slice = swz / 24;
  const int rem   = swz - slice * 24;
  const int mt    = rem / 3;
  const int nt    = rem - mt * 3;

  const float* xbase = x    + (size_t)mt * BM * XROW + (size_t)slice * DIN;
  const float* wbase = w    + (size_t)slice * WSLICE + nt * BN;
  const float* bbase = bias + (size_t)slice * DOUT   + nt * BN;
  float*       obase = out  + (size_t)mt * BM * XROW + (size_t)slice * DOUT + nt * BN;

  // A staging: lanes 0..7 cover one 128B row chunk (coalesced)
  const int a_c4   = tid & 7;
  const int a_row0 = tid >> 3;
  // B staging: lanes 0..31 cover 512B contiguous of one w row (coalesced)
  const int b_o4   = tid & 31;
  const int b_kr   = tid >> 5;           // 0..7; rows b_kr + 8j

  float gav[4][4];
  float gbv[4][4];

  auto G2R = [&](int k0) {
#pragma unroll
    for (int i = 0; i < 4; ++i) {
      const float4 v = *reinterpret_cast<const float4*>(
          xbase + (size_t)(a_row0 + 32 * i) * XROW + k0 + a_c4 * 4);
      gav[i][0] = v.x; gav[i][1] = v.y; gav[i][2] = v.z; gav[i][3] = v.w;
    }
#pragma unroll
    for (int j = 0; j < 4; ++j) {
      const float4 v = *reinterpret_cast<const float4*>(
          wbase + (size_t)(k0 + b_kr + 8 * j) * DOUT + b_o4 * 4);
      gbv[j][0] = v.x; gbv[j][1] = v.y; gbv[j][2] = v.z; gbv[j][3] = v.w;
    }
  };

  auto R2L = [&](int buf) {
#pragma unroll
    for (int i = 0; i < 4; ++i) {
      *reinterpret_cast<uint2*>(
          &lA[buf][(a_row0 + 32 * i) * PITCH + a_c4 * 4]) =
          pack4(gav[i][0], gav[i][1], gav[i][2], gav[i][3]);
    }
#pragma unroll
    for (int j = 0; j < 4; ++j) {
      *reinterpret_cast<uint2*>(
          &lB[buf][(b_kr + 8 * j) * BPITCH + b_o4 * 4]) =
          pack4(gbv[j][0], gbv[j][1], gbv[j][2], gbv[j][3]);
    }
  };

  f32x16 acc[2][2];
#pragma unroll
  for (int m = 0; m < 2; ++m)
#pragma unroll
    for (int n = 0; n < 2; ++n)
#pragma unroll
      for (int r = 0; r < 16; ++r)
        acc[m][n][r] = 0.f;

  G2R(0);
  R2L(0);
  barrier_nodrain();
  G2R(BK);

  auto STEP = [&](int ks, int cb) {
    if (ks + 1 < NK) R2L(cb ^ 1);
    if (ks + 2 < NK) G2R((ks + 2) * BK);
    bf16x8 af[2][2];   // [kk][m]
    bf16x8 bfv[2][2];  // [kk][n]
#pragma unroll
    for (int kk = 0; kk < 2; ++kk)
#pragma unroll
      for (int m = 0; m < 2; ++m)
        af[kk][m] = *reinterpret_cast<const bf16x8*>(
            &lA[cb][(wm * 64 + m * 32 + l31) * PITCH + kk * 16 + kHi]);
#pragma unroll
    for (int kk = 0; kk < 2; ++kk)
#pragma unroll
      for (int n = 0; n < 2; ++n)
#pragma unroll
        for (int j = 0; j < 8; ++j)
          bfv[kk][n][j] = lB[cb][(kk * 16 + kHi + j) * BPITCH + wn * 64 + n * 32 + l31];
#pragma unroll
    for (int kk = 0; kk < 2; ++kk)
#pragma unroll
      for (int m = 0; m < 2; ++m)
#pragma unroll
        for (int n = 0; n < 2; ++n)
          acc[m][n] = __builtin_amdgcn_mfma_f32_32x32x16_bf16(
              af[kk][m], bfv[kk][n], acc[m][n], 0, 0, 0);
    barrier_nodrain();
  };

#pragma unroll
  for (int ks = 0; ks < NK; ks += 2) {
    STEP(ks, 0);
    STEP(ks + 1, 1);
  }

  // Epilogue. 32x32 D frag: col = lane&31, row = (reg&3) + 8*(reg>>2) + 4*(lane>>5)
  float bv[2];
#pragma unroll
  for (int n = 0; n < 2; ++n) bv[n] = bbase[wn * 64 + n * 32 + l31];

  const int rbase = wm * 64 + ((lane >> 5) << 2);
#pragma unroll
  for (int m = 0; m < 2; ++m) {
#pragma unroll
    for (int n = 0; n < 2; ++n) {
      const int c = wn * 64 + n * 32 + l31;
#pragma unroll
      for (int r = 0; r < 16; ++r) {
        const int row = rbase + m * 32 + (r & 3) + 8 * (r >> 2);
        obase[(size_t)row * XROW + c] = acc[m][n][r] + bv[n];
      }
    }
  }
}

extern "C" void kernel_launch(void* const* d_in, const int* in_sizes, int n_in,
                              void* d_out, int out_size, void* d_ws, size_t ws_size,
                              hipStream_t stream) {
  const float* x  = (const float*)d_in[0];
  const float* w  = (const float*)d_in[1];
  const float* b  = (const float*)d_in[2];
  float* out      = (float*)d_out;
  const int grid  = NPOS * (BATCH / BM) * (DOUT / BN);  // 2400
  nlinear_kernel<<<grid, 256, 0, stream>>>(x, w, b, out);
}